// Round 2
// baseline (150.672 us; speedup 1.0000x reference)
//
#include <hip/hip_runtime.h>
#include <hip/hip_bf16.h>
#include <math.h>

// Problem constants (from reference setup_inputs)
constexpr int B = 4, S = 10, N = 2048, D = 128;

constexpr int KS      = 8;            // database slices per (b,s,dir)
constexpr int SLICE   = N / KS;       // 256 db points per block
constexpr int QCHUNK  = 4;            // query chunks per (b,s,dir,slice)
constexpr int QPB     = N / QCHUNK;   // 512 queries per chamfer block
constexpr int T1      = 64;           // k1 chamfer block = 1 wave
constexpr int QPT     = QPB / T1;     // 8 queries per thread
constexpr int CHAM_BLOCKS = B * S * 2 * KS * QCHUNK;   // 2560
constexpr int TOTQ    = B * S * 2 * N;        // 163840 (query, dir) pairs
constexpr int TEMP_ELEMS = B * (S - 1) * N;   // 73728
constexpr int TEMP_BLOCKS = 16;
constexpr int T2      = 256;
constexpr int TEMP_PER_BLOCK = TEMP_ELEMS / TEMP_BLOCKS;  // 4608 = 18*256
constexpr int KL_ELEMS = B * S * D;           // 5120 = 20*256
constexpr int K2_BLOCKS = TOTQ / T2;          // 640
constexpr int K2_GRID   = K2_BLOCKS + TEMP_BLOCKS + 1;   // 657

// ws layout (floats) — partials/chsum identical to previous version:
//   [0 .. KS*TOTQ)                 partial d^2 per (slice, query)
//   [KS*TOTQ .. +K2_BLOCKS)        per-block chamfer distance sums
//   then TEMP_BLOCKS temporal partials, 1 kl partial, 1 ticket counter
constexpr size_t WS_PARTIAL = 0;
constexpr size_t WS_CHSUM   = (size_t)KS * TOTQ;
constexpr size_t WS_TPART   = WS_CHSUM + K2_BLOCKS;
constexpr size_t WS_KL      = WS_TPART + TEMP_BLOCKS;
constexpr size_t WS_CNT     = WS_KL + 1;

typedef float v2f __attribute__((ext_vector_type(2)));

__device__ __forceinline__ v2f pk_fma(v2f a, v2f b, v2f c) {
    v2f d;
    asm("v_pk_fma_f32 %0, %1, %2, %3" : "=v"(d) : "v"(a), "v"(b), "v"(c));
    return d;
}

// valid result on thread 0 only (256-thread blocks)
__device__ __forceinline__ float block_sum(float v, float* red) {
    #pragma unroll
    for (int off = 32; off > 0; off >>= 1)
        v += __shfl_down(v, off, 64);
    const int wid = threadIdx.x >> 6;
    if ((threadIdx.x & 63) == 0) red[wid] = v;
    __syncthreads();
    return red[0] + red[1] + red[2] + red[3];
}

// ---------------------------------------------------------------------------
// K1: 2560 single-wave chamfer blocks, QPT=8
// ---------------------------------------------------------------------------
__global__ __launch_bounds__(64) void k1_kernel(
        const float* __restrict__ pred, const float* __restrict__ tgt,
        float* __restrict__ ws) {
    // pair-interleaved db: [2p]={x0,x1,y0,y1} [2p+1]={z0,z1,m0,m1}; +2 pad for prefetch
    __shared__ float4 db[SLICE + 2];

    const int bid = blockIdx.x;
    const int tid = threadIdx.x;

    if (bid == 0 && tid == 0) ws[WS_CNT] = 0.0f;   // reset k2 ticket counter

    const int ks  = bid & (KS - 1);
    const int dir = (bid >> 3) & 1;
    const int qc  = (bid >> 4) & (QCHUNK - 1);
    const int bs  = bid >> 6;                 // b*S + s  (0..39)
    const float* qb  = (dir ? tgt : pred) + (size_t)bs * N * 3;  // queries
    const float* dbp = (dir ? pred : tgt) + (size_t)bs * N * 3;  // database

    // stage 256 db points (128 pairs), pair-interleaved, m = -0.5*|g|^2
    // thread t stages pairs t and t+64 (32B-stride writes: 4-way bank alias, 2 instrs)
    #pragma unroll
    for (int j = 0; j < 2; ++j) {
        const int pr = tid + 64 * j;              // pair index 0..127
        const int p0 = ks * SLICE + 2 * pr;       // first point of the pair
        const float2* dp2 = (const float2*)(dbp + 3 * p0);  // 8B-aligned
        const float2 a = dp2[0], b2 = dp2[1], c = dp2[2];
        const float x0 = a.x, y0 = a.y, z0 = b2.x;
        const float x1 = b2.y, y1 = c.x, z1 = c.y;
        db[2 * pr + 0] = make_float4(x0, x1, y0, y1);
        db[2 * pr + 1] = make_float4(z0, z1,
                                     -0.5f * (x0 * x0 + y0 * y0 + z0 * z0),
                                     -0.5f * (x1 * x1 + y1 * y1 + z1 * z1));
    }

    // load 8 queries into registers (splatted for packed fma)
    v2f px2[QPT], py2[QPT], pz2[QPT];
    float pn[QPT], acc[QPT];
    #pragma unroll
    for (int i = 0; i < QPT; ++i) {
        const int q = qc * QPB + tid + T1 * i;
        const float x = qb[3 * q + 0], y = qb[3 * q + 1], z = qb[3 * q + 2];
        px2[i] = (v2f){x, x};
        py2[i] = (v2f){y, y};
        pz2[i] = (v2f){z, z};
        pn[i]  = x * x + y * y + z * z;
        acc[i] = -1e30f;
    }
    __syncthreads();   // single wave: compiles to waitcnt + cheap barrier

    // max over slice of score = p.g - 0.5|g|^2 (2 db points per packed op)
    // software-pipelined: prefetch next iteration's LDS pair while computing
    float4 cA = db[0], cB = db[1];
    #pragma unroll 2
    for (int p = 0; p < SLICE / 2; ++p) {
        const float4 nA = db[2 * p + 2];   // last iter reads pad (unused)
        const float4 nB = db[2 * p + 3];
        const v2f x01 = (v2f){cA.x, cA.y};
        const v2f y01 = (v2f){cA.z, cA.w};
        const v2f z01 = (v2f){cB.x, cB.y};
        const v2f m01 = (v2f){cB.z, cB.w};
        #pragma unroll
        for (int i = 0; i < QPT; ++i) {
            v2f t = pk_fma(pz2[i], z01, m01);
            t = pk_fma(py2[i], y01, t);
            t = pk_fma(px2[i], x01, t);
            acc[i] = fmaxf(acc[i], fmaxf(t.x, t.y));   // v_max3_f32
        }
        cA = nA; cB = nB;
    }

    // partial d^2 for this slice (same values & global addresses as before)
    float* part = ws + WS_PARTIAL + (size_t)ks * TOTQ
                + (size_t)(bs * 2 + dir) * N + (size_t)qc * QPB;
    #pragma unroll
    for (int i = 0; i < QPT; ++i)
        part[tid + T1 * i] = pn[i] - 2.0f * acc[i];
}

// ---------------------------------------------------------------------------
// K2: blocks [0,640): per-query min over KS slices, sqrt, per-block sum
//     blocks [640,656): temporal partials;  block 656: kl partial
//     last-finishing block performs the final combine (old k3, same order)
// ---------------------------------------------------------------------------
__global__ __launch_bounds__(256) void k2_kernel(
        const float* __restrict__ pred,
        const float* __restrict__ prior_mean, const float* __restrict__ prior_lv,
        const float* __restrict__ post_mean,  const float* __restrict__ post_lv,
        float* __restrict__ ws, float* __restrict__ out) {
    __shared__ float red[4];
    __shared__ int amLast;
    const int bid = blockIdx.x;
    const int tid = threadIdx.x;

    if (bid < K2_BLOCKS) {
        // chamfer reduce (bit-identical to previous k2)
        const int u = bid * T2 + tid;   // < TOTQ
        const float* part = ws + WS_PARTIAL;
        float d2 = part[u];
        #pragma unroll
        for (int k = 1; k < KS; ++k)
            d2 = fminf(d2, part[(size_t)k * TOTQ + u]);
        const float d = sqrtf(fmaxf(d2, 0.0f));
        const float tot = block_sum(d, red);
        if (tid == 0) ws[WS_CHSUM + bid] = tot;
    } else if (bid < K2_BLOCKS + TEMP_BLOCKS) {
        // temporal: sum ||pred[:,s+1]-pred[:,s]|| (bit-identical to previous)
        const int tb = bid - K2_BLOCKS;
        float s = 0.0f;
        for (int it = 0; it < TEMP_PER_BLOCK / T2; ++it) {
            const int i = tb * TEMP_PER_BLOCK + it * T2 + tid;
            const int b = i / ((S - 1) * N);
            const int r = i % ((S - 1) * N);
            const float* p0 = pred + (size_t)(b * S * N + r) * 3;
            const float* p1 = p0 + (size_t)N * 3;
            const float dx = p1[0] - p0[0];
            const float dy = p1[1] - p0[1];
            const float dz = p1[2] - p0[2];
            s += sqrtf(dx * dx + dy * dy + dz * dz);
        }
        const float tot = block_sum(s, red);
        if (tid == 0) ws[WS_TPART + tb] = tot;
    } else {
        // kl term sum (bit-identical to previous)
        float s = 0.0f;
        for (int it = 0; it < KL_ELEMS / T2; ++it) {
            const int i = it * T2 + tid;
            const float a  = prior_lv[i];
            const float bb = post_lv[i];
            const float dm = post_mean[i] - prior_mean[i];
            s += a - bb + (expf(bb) + dm * dm) * expf(-a) - 1.0f;
        }
        const float tot = block_sum(s, red);
        if (tid == 0) ws[WS_KL] = tot;
    }

    // ----- last-block ticket: fold old k3 in (combine order preserved) -----
    __threadfence();
    if (tid == 0) {
        const unsigned t = atomicAdd((unsigned*)(ws + WS_CNT), 1u);
        amLast = (t == K2_GRID - 1);
    }
    __syncthreads();
    if (amLast) {
        __threadfence();
        float s = 0.0f;
        for (int i = tid; i < K2_BLOCKS; i += T2)
            s += ws[WS_CHSUM + i];
        const float tot = block_sum(s, red);
        if (tid == 0) {
            float tsum = 0.0f;
            for (int i = 0; i < TEMP_BLOCKS; ++i) tsum += ws[WS_TPART + i];
            const float recon    = tot / (float)(B * S * N);
            const float kl       = 0.5f * ws[WS_KL] / (float)(B * S);
            const float temporal = tsum / (float)TEMP_ELEMS;
            out[0] = recon + kl + 0.1f * temporal;
            out[1] = recon;
            out[2] = kl;
            out[3] = temporal;
            out[4] = 0.0f;
        }
    }
}

extern "C" void kernel_launch(void* const* d_in, const int* in_sizes, int n_in,
                              void* d_out, int out_size, void* d_ws, size_t ws_size,
                              hipStream_t stream) {
    const float* pred = (const float*)d_in[0];
    const float* tgt  = (const float*)d_in[1];
    const float* pm   = (const float*)d_in[2];
    const float* plv  = (const float*)d_in[3];
    const float* qm   = (const float*)d_in[4];
    const float* qlv  = (const float*)d_in[5];
    float* out = (float*)d_out;
    float* ws  = (float*)d_ws;

    k1_kernel<<<CHAM_BLOCKS, T1, 0, stream>>>(pred, tgt, ws);
    k2_kernel<<<K2_GRID, T2, 0, stream>>>(pred, pm, plv, qm, qlv, ws, out);
}

// Round 4
// 106.202 us; speedup vs baseline: 1.4187x; 1.4187x over previous
//
#include <hip/hip_runtime.h>
#include <hip/hip_bf16.h>
#include <math.h>

// Problem constants (from reference setup_inputs)
constexpr int B = 4, S = 10, N = 2048, D = 128;

constexpr int KS      = 8;            // database slices per (b,s,dir)
constexpr int SLICE   = N / KS;       // 256 db points per block
constexpr int QCHUNK  = 2;            // query chunks per (b,s,dir,slice)
constexpr int QPB     = N / QCHUNK;   // 1024 queries per chamfer block
constexpr int THREADS = 256;
constexpr int QPT     = QPB / THREADS;  // 4 queries per thread
constexpr int CHAM_BLOCKS = B * S * 2 * KS * QCHUNK;   // 1280
constexpr int TOTQ    = B * S * 2 * N;        // 163840 (query, dir) pairs
constexpr int TEMP_ELEMS = B * (S - 1) * N;   // 73728
constexpr int TEMP_BLOCKS = 16;
constexpr int TEMP_PER_BLOCK = TEMP_ELEMS / TEMP_BLOCKS;  // 4608 = 18*256
constexpr int KL_ELEMS = B * S * D;           // 5120 = 20*256
constexpr int K2_BLOCKS = TOTQ / THREADS;     // 640

// ws layout (floats) — identical to R0/R1:
//   [0 .. KS*TOTQ)                 partial d^2 per (slice, query)
//   [KS*TOTQ .. +K2_BLOCKS)        per-block chamfer distance sums (K2)
//   then TEMP_BLOCKS temporal partials, then 1 kl partial
constexpr size_t WS_PARTIAL = 0;
constexpr size_t WS_CHSUM   = (size_t)KS * TOTQ;
constexpr size_t WS_TPART   = WS_CHSUM + K2_BLOCKS;
constexpr size_t WS_KL      = WS_TPART + TEMP_BLOCKS;

typedef float v2f __attribute__((ext_vector_type(2)));

__device__ __forceinline__ v2f pk_fma(v2f a, v2f b, v2f c) {
    v2f d;
    asm("v_pk_fma_f32 %0, %1, %2, %3" : "=v"(d) : "v"(a), "v"(b), "v"(c));
    return d;
}

// valid result on thread 0 only
__device__ __forceinline__ float block_sum(float v, float* red) {
    #pragma unroll
    for (int off = 32; off > 0; off >>= 1)
        v += __shfl_down(v, off, 64);
    const int wid = threadIdx.x >> 6;
    if ((threadIdx.x & 63) == 0) red[wid] = v;
    __syncthreads();
    return red[0] + red[1] + red[2] + red[3];
}

// ---------------------------------------------------------------------------
// K1: blocks [0,1280): chamfer partials; [1280,1296): temporal; 1296: kl
// ---------------------------------------------------------------------------
__global__ __launch_bounds__(256) void k1_kernel(
        const float* __restrict__ pred, const float* __restrict__ tgt,
        const float* __restrict__ prior_mean, const float* __restrict__ prior_lv,
        const float* __restrict__ post_mean,  const float* __restrict__ post_lv,
        float* __restrict__ ws) {
    // pair-interleaved db: [2p]={x0,x1,y0,y1} [2p+1]={z0,z1,m0,m1}
    // read back as v2f quads: db2[4p]={x01} [4p+1]={y01} [4p+2]={z01} [4p+3]={m01}
    __shared__ float4 db[SLICE];
    __shared__ float red[4];

    const int bid = blockIdx.x;
    const int tid = threadIdx.x;

    if (bid < CHAM_BLOCKS) {
        const int ks  = bid & (KS - 1);
        const int dir = (bid >> 3) & 1;
        const int qc  = (bid >> 4) & (QCHUNK - 1);
        const int bs  = bid >> 5;                 // b*S + s  (0..39)
        const float* qb  = (dir ? tgt : pred) + (size_t)bs * N * 3;  // queries
        const float* dbp = (dir ? pred : tgt) + (size_t)bs * N * 3;  // database

        // stage 256 db points (128 pairs), pair-interleaved, m = -0.5*|g|^2
        if (tid < SLICE / 2) {
            const int p0 = ks * SLICE + 2 * tid;
            const float2* dp2 = (const float2*)(dbp + 3 * p0);  // 8B-aligned
            const float2 a = dp2[0], b2 = dp2[1], c = dp2[2];
            const float x0 = a.x, y0 = a.y, z0 = b2.x;
            const float x1 = b2.y, y1 = c.x, z1 = c.y;
            db[2 * tid + 0] = make_float4(x0, x1, y0, y1);
            db[2 * tid + 1] = make_float4(z0, z1,
                                          -0.5f * (x0 * x0 + y0 * y0 + z0 * z0),
                                          -0.5f * (x1 * x1 + y1 * y1 + z1 * z1));
        }

        // load 4 queries into registers (splatted once, loop-invariant)
        v2f px2[QPT], py2[QPT], pz2[QPT];
        float pn[QPT], acc[QPT];
        #pragma unroll
        for (int i = 0; i < QPT; ++i) {
            const int q = qc * QPB + tid + THREADS * i;
            const float x = qb[3 * q + 0], y = qb[3 * q + 1], z = qb[3 * q + 2];
            px2[i] = (v2f){x, x};
            py2[i] = (v2f){y, y};
            pz2[i] = (v2f){z, z};
            pn[i]  = x * x + y * y + z * z;
            acc[i] = -1e30f;
        }
        __syncthreads();

        // max over slice of score = p.g - 0.5|g|^2 (2 db points per packed op)
        // v2f loads land directly in the asm's register pairs: no extraction movs
        const v2f* db2 = (const v2f*)db;
        #pragma unroll 4
        for (int p = 0; p < SLICE / 2; ++p) {
            const v2f x01 = db2[4 * p + 0];
            const v2f y01 = db2[4 * p + 1];
            const v2f z01 = db2[4 * p + 2];
            const v2f m01 = db2[4 * p + 3];
            #pragma unroll
            for (int i = 0; i < QPT; ++i) {
                v2f t = pk_fma(pz2[i], z01, m01);
                t = pk_fma(py2[i], y01, t);
                t = pk_fma(px2[i], x01, t);
                acc[i] = fmaxf(acc[i], fmaxf(t.x, t.y));   // v_max3_f32
            }
        }

        // partial d^2 for this slice (same values & global addresses as before)
        float* part = ws + WS_PARTIAL + (size_t)ks * TOTQ
                    + (size_t)(bs * 2 + dir) * N + (size_t)qc * QPB;
        #pragma unroll
        for (int i = 0; i < QPT; ++i)
            part[tid + THREADS * i] = pn[i] - 2.0f * acc[i];
    } else if (bid < CHAM_BLOCKS + TEMP_BLOCKS) {
        // temporal: sum ||pred[:,s+1]-pred[:,s]||
        const int tb = bid - CHAM_BLOCKS;
        float s = 0.0f;
        for (int it = 0; it < TEMP_PER_BLOCK / THREADS; ++it) {
            const int i = tb * TEMP_PER_BLOCK + it * THREADS + tid;
            const int b = i / ((S - 1) * N);
            const int r = i % ((S - 1) * N);
            const float* p0 = pred + (size_t)(b * S * N + r) * 3;
            const float* p1 = p0 + (size_t)N * 3;
            const float dx = p1[0] - p0[0];
            const float dy = p1[1] - p0[1];
            const float dz = p1[2] - p0[2];
            s += sqrtf(dx * dx + dy * dy + dz * dz);
        }
        const float tot = block_sum(s, red);
        if (tid == 0) ws[WS_TPART + tb] = tot;
    } else {
        // kl term sum
        float s = 0.0f;
        for (int it = 0; it < KL_ELEMS / THREADS; ++it) {
            const int i = it * THREADS + tid;
            const float a  = prior_lv[i];
            const float bb = post_lv[i];
            const float dm = post_mean[i] - prior_mean[i];
            s += a - bb + (expf(bb) + dm * dm) * expf(-a) - 1.0f;
        }
        const float tot = block_sum(s, red);
        if (tid == 0) ws[WS_KL] = tot;
    }
}

// ---------------------------------------------------------------------------
// K2: per query min over KS slices, sqrt, per-block sum (640 blocks x 256)
// (unchanged — bit-identical reduction order)
// ---------------------------------------------------------------------------
__global__ __launch_bounds__(256) void k2_kernel(float* __restrict__ ws) {
    __shared__ float red[4];
    const int u = blockIdx.x * THREADS + threadIdx.x;   // < TOTQ
    const float* part = ws + WS_PARTIAL;
    float d2 = part[u];
    #pragma unroll
    for (int k = 1; k < KS; ++k)
        d2 = fminf(d2, part[(size_t)k * TOTQ + u]);
    const float d = sqrtf(fmaxf(d2, 0.0f));
    const float tot = block_sum(d, red);
    if (threadIdx.x == 0) ws[WS_CHSUM + blockIdx.x] = tot;
}

// ---------------------------------------------------------------------------
// K3: final combine (unchanged)
// ---------------------------------------------------------------------------
__global__ __launch_bounds__(256) void k3_kernel(const float* __restrict__ ws,
                                                 float* __restrict__ out) {
    __shared__ float red[4];
    float s = 0.0f;
    for (int i = threadIdx.x; i < K2_BLOCKS; i += THREADS)
        s += ws[WS_CHSUM + i];
    const float tot = block_sum(s, red);
    if (threadIdx.x == 0) {
        float tsum = 0.0f;
        for (int i = 0; i < TEMP_BLOCKS; ++i) tsum += ws[WS_TPART + i];
        const float recon    = tot / (float)(B * S * N);
        const float kl       = 0.5f * ws[WS_KL] / (float)(B * S);
        const float temporal = tsum / (float)TEMP_ELEMS;
        out[0] = recon + kl + 0.1f * temporal;
        out[1] = recon;
        out[2] = kl;
        out[3] = temporal;
        out[4] = 0.0f;
    }
}

extern "C" void kernel_launch(void* const* d_in, const int* in_sizes, int n_in,
                              void* d_out, int out_size, void* d_ws, size_t ws_size,
                              hipStream_t stream) {
    const float* pred = (const float*)d_in[0];
    const float* tgt  = (const float*)d_in[1];
    const float* pm   = (const float*)d_in[2];
    const float* plv  = (const float*)d_in[3];
    const float* qm   = (const float*)d_in[4];
    const float* qlv  = (const float*)d_in[5];
    float* out = (float*)d_out;
    float* ws  = (float*)d_ws;

    k1_kernel<<<CHAM_BLOCKS + TEMP_BLOCKS + 1, THREADS, 0, stream>>>(
        pred, tgt, pm, plv, qm, qlv, ws);
    k2_kernel<<<TOTQ / THREADS, THREADS, 0, stream>>>(ws);
    k3_kernel<<<1, THREADS, 0, stream>>>(ws, out);
}

// Round 5
// 105.925 us; speedup vs baseline: 1.4224x; 1.0026x over previous
//
#include <hip/hip_runtime.h>
#include <hip/hip_bf16.h>
#include <math.h>

// Problem constants (from reference setup_inputs)
constexpr int B = 4, S = 10, N = 2048, D = 128;

constexpr int KS      = 16;           // database slices per (b,s,dir)
constexpr int SLICE   = N / KS;       // 128 db points per block
constexpr int THREADS = 256;
constexpr int QPB     = N;            // all 2048 queries per chamfer block
constexpr int QPT     = QPB / THREADS;  // 8 queries per thread
constexpr int CHAM_BLOCKS = B * S * 2 * KS;   // 1280
constexpr int TOTQ    = B * S * 2 * N;        // 163840 (query, dir) pairs
constexpr int TEMP_ELEMS = B * (S - 1) * N;   // 73728
constexpr int TEMP_BLOCKS = 16;
constexpr int TEMP_PER_BLOCK = TEMP_ELEMS / TEMP_BLOCKS;  // 4608 = 18*256
constexpr int KL_ELEMS = B * S * D;           // 5120 = 20*256
constexpr int K2_BLOCKS = TOTQ / THREADS;     // 640

// ws layout (floats):
//   [0 .. KS*TOTQ)                 partial d^2 per (slice, query)   (10.5 MB)
//   [KS*TOTQ .. +K2_BLOCKS)        per-block chamfer distance sums (K2)
//   then TEMP_BLOCKS temporal partials, then 1 kl partial
constexpr size_t WS_PARTIAL = 0;
constexpr size_t WS_CHSUM   = (size_t)KS * TOTQ;
constexpr size_t WS_TPART   = WS_CHSUM + K2_BLOCKS;
constexpr size_t WS_KL      = WS_TPART + TEMP_BLOCKS;

typedef float v2f __attribute__((ext_vector_type(2)));

__device__ __forceinline__ v2f pk_fma(v2f a, v2f b, v2f c) {
    v2f d;
    asm("v_pk_fma_f32 %0, %1, %2, %3" : "=v"(d) : "v"(a), "v"(b), "v"(c));
    return d;
}

// valid result on thread 0 only
__device__ __forceinline__ float block_sum(float v, float* red) {
    #pragma unroll
    for (int off = 32; off > 0; off >>= 1)
        v += __shfl_down(v, off, 64);
    const int wid = threadIdx.x >> 6;
    if ((threadIdx.x & 63) == 0) red[wid] = v;
    __syncthreads();
    return red[0] + red[1] + red[2] + red[3];
}

// ---------------------------------------------------------------------------
// K1: blocks [0,1280): chamfer partials (slice of 128 db pts x 2048 queries);
//     [1280,1296): temporal; 1296: kl
// ---------------------------------------------------------------------------
__global__ __launch_bounds__(256) void k1_kernel(
        const float* __restrict__ pred, const float* __restrict__ tgt,
        const float* __restrict__ prior_mean, const float* __restrict__ prior_lv,
        const float* __restrict__ post_mean,  const float* __restrict__ post_lv,
        float* __restrict__ ws) {
    // pair-interleaved db: [2p]={x0,x1,y0,y1} [2p+1]={z0,z1,m0,m1}
    // read back as v2f quads: db2[4p]={x01} [4p+1]={y01} [4p+2]={z01} [4p+3]={m01}
    __shared__ float4 db[SLICE];
    __shared__ float red[4];

    const int bid = blockIdx.x;
    const int tid = threadIdx.x;

    if (bid < CHAM_BLOCKS) {
        const int ks  = bid & (KS - 1);
        const int dir = (bid >> 4) & 1;
        const int bs  = bid >> 5;                 // b*S + s  (0..39)
        const float* qb  = (dir ? tgt : pred) + (size_t)bs * N * 3;  // queries
        const float* dbp = (dir ? pred : tgt) + (size_t)bs * N * 3;  // database

        // stage 128 db points (64 pairs), pair-interleaved, m = -0.5*|g|^2
        if (tid < SLICE / 2) {
            const int p0 = ks * SLICE + 2 * tid;
            const float2* dp2 = (const float2*)(dbp + 3 * p0);  // 24B-aligned
            const float2 a = dp2[0], b2 = dp2[1], c = dp2[2];
            const float x0 = a.x, y0 = a.y, z0 = b2.x;
            const float x1 = b2.y, y1 = c.x, z1 = c.y;
            db[2 * tid + 0] = make_float4(x0, x1, y0, y1);
            db[2 * tid + 1] = make_float4(z0, z1,
                                          -0.5f * (x0 * x0 + y0 * y0 + z0 * z0),
                                          -0.5f * (x1 * x1 + y1 * y1 + z1 * z1));
        }

        // load 8 queries into registers (splatted once, loop-invariant)
        v2f px2[QPT], py2[QPT], pz2[QPT];
        float pn[QPT], acc[QPT];
        #pragma unroll
        for (int i = 0; i < QPT; ++i) {
            const int q = tid + THREADS * i;
            const float x = qb[3 * q + 0], y = qb[3 * q + 1], z = qb[3 * q + 2];
            px2[i] = (v2f){x, x};
            py2[i] = (v2f){y, y};
            pz2[i] = (v2f){z, z};
            pn[i]  = x * x + y * y + z * z;
            acc[i] = -1e30f;
        }
        __syncthreads();

        // max over slice of score = p.g - 0.5|g|^2 (2 db points per packed op)
        // 2 LDS reads amortized over 8 queries x 4 VALU = 32 core ops/iter
        const v2f* db2 = (const v2f*)db;
        #pragma unroll 2
        for (int p = 0; p < SLICE / 2; ++p) {
            const v2f x01 = db2[4 * p + 0];
            const v2f y01 = db2[4 * p + 1];
            const v2f z01 = db2[4 * p + 2];
            const v2f m01 = db2[4 * p + 3];
            #pragma unroll
            for (int i = 0; i < QPT; ++i) {
                v2f t = pk_fma(pz2[i], z01, m01);
                t = pk_fma(py2[i], y01, t);
                t = pk_fma(px2[i], x01, t);
                acc[i] = fmaxf(acc[i], fmaxf(t.x, t.y));   // v_max3_f32
            }
        }

        // partial d^2 for this slice
        float* part = ws + WS_PARTIAL + (size_t)ks * TOTQ + (size_t)(bs * 2 + dir) * N;
        #pragma unroll
        for (int i = 0; i < QPT; ++i)
            part[tid + THREADS * i] = pn[i] - 2.0f * acc[i];
    } else if (bid < CHAM_BLOCKS + TEMP_BLOCKS) {
        // temporal: sum ||pred[:,s+1]-pred[:,s]||
        const int tb = bid - CHAM_BLOCKS;
        float s = 0.0f;
        for (int it = 0; it < TEMP_PER_BLOCK / THREADS; ++it) {
            const int i = tb * TEMP_PER_BLOCK + it * THREADS + tid;
            const int b = i / ((S - 1) * N);
            const int r = i % ((S - 1) * N);
            const float* p0 = pred + (size_t)(b * S * N + r) * 3;
            const float* p1 = p0 + (size_t)N * 3;
            const float dx = p1[0] - p0[0];
            const float dy = p1[1] - p0[1];
            const float dz = p1[2] - p0[2];
            s += sqrtf(dx * dx + dy * dy + dz * dz);
        }
        const float tot = block_sum(s, red);
        if (tid == 0) ws[WS_TPART + tb] = tot;
    } else {
        // kl term sum
        float s = 0.0f;
        for (int it = 0; it < KL_ELEMS / THREADS; ++it) {
            const int i = it * THREADS + tid;
            const float a  = prior_lv[i];
            const float bb = post_lv[i];
            const float dm = post_mean[i] - prior_mean[i];
            s += a - bb + (expf(bb) + dm * dm) * expf(-a) - 1.0f;
        }
        const float tot = block_sum(s, red);
        if (tid == 0) ws[WS_KL] = tot;
    }
}

// ---------------------------------------------------------------------------
// K2: per query min over KS slices, sqrt, per-block sum (640 blocks x 256)
// (min over 16 — exactly associative; same final d per query as before)
// ---------------------------------------------------------------------------
__global__ __launch_bounds__(256) void k2_kernel(float* __restrict__ ws) {
    __shared__ float red[4];
    const int u = blockIdx.x * THREADS + threadIdx.x;   // < TOTQ
    const float* part = ws + WS_PARTIAL;
    float d2 = part[u];
    #pragma unroll
    for (int k = 1; k < KS; ++k)
        d2 = fminf(d2, part[(size_t)k * TOTQ + u]);
    const float d = sqrtf(fmaxf(d2, 0.0f));
    const float tot = block_sum(d, red);
    if (threadIdx.x == 0) ws[WS_CHSUM + blockIdx.x] = tot;
}

// ---------------------------------------------------------------------------
// K3: final combine (unchanged)
// ---------------------------------------------------------------------------
__global__ __launch_bounds__(256) void k3_kernel(const float* __restrict__ ws,
                                                 float* __restrict__ out) {
    __shared__ float red[4];
    float s = 0.0f;
    for (int i = threadIdx.x; i < K2_BLOCKS; i += THREADS)
        s += ws[WS_CHSUM + i];
    const float tot = block_sum(s, red);
    if (threadIdx.x == 0) {
        float tsum = 0.0f;
        for (int i = 0; i < TEMP_BLOCKS; ++i) tsum += ws[WS_TPART + i];
        const float recon    = tot / (float)(B * S * N);
        const float kl       = 0.5f * ws[WS_KL] / (float)(B * S);
        const float temporal = tsum / (float)TEMP_ELEMS;
        out[0] = recon + kl + 0.1f * temporal;
        out[1] = recon;
        out[2] = kl;
        out[3] = temporal;
        out[4] = 0.0f;
    }
}

extern "C" void kernel_launch(void* const* d_in, const int* in_sizes, int n_in,
                              void* d_out, int out_size, void* d_ws, size_t ws_size,
                              hipStream_t stream) {
    const float* pred = (const float*)d_in[0];
    const float* tgt  = (const float*)d_in[1];
    const float* pm   = (const float*)d_in[2];
    const float* plv  = (const float*)d_in[3];
    const float* qm   = (const float*)d_in[4];
    const float* qlv  = (const float*)d_in[5];
    float* out = (float*)d_out;
    float* ws  = (float*)d_ws;

    k1_kernel<<<CHAM_BLOCKS + TEMP_BLOCKS + 1, THREADS, 0, stream>>>(
        pred, tgt, pm, plv, qm, qlv, ws);
    k2_kernel<<<TOTQ / THREADS, THREADS, 0, stream>>>(ws);
    k3_kernel<<<1, THREADS, 0, stream>>>(ws, out);
}

// Round 6
// 103.676 us; speedup vs baseline: 1.4533x; 1.0217x over previous
//
#include <hip/hip_runtime.h>
#include <hip/hip_bf16.h>
#include <math.h>

// Problem constants (from reference setup_inputs)
constexpr int B = 4, S = 10, N = 2048, D = 128;

constexpr int KS      = 16;           // database slices per (b,s,dir)
constexpr int SLICE   = N / KS;       // 128 db points per block
constexpr int THREADS = 256;
constexpr int QPT     = N / THREADS;  // 8 queries per thread (all N per block)
constexpr int CHAM_BLOCKS = B * S * 2 * KS;   // 1280
constexpr int TOTQ    = B * S * 2 * N;        // 163840 (query, dir) pairs
constexpr int TEMP_ELEMS = B * (S - 1) * N;   // 73728
constexpr int TEMP_BLOCKS = 16;
constexpr int TEMP_PER_BLOCK = TEMP_ELEMS / TEMP_BLOCKS;  // 4608 = 18*256
constexpr int KL_ELEMS = B * S * D;           // 5120 = 20*256
constexpr int K2_BLOCKS = TOTQ / THREADS;     // 640
constexpr int K2_GRID   = K2_BLOCKS + TEMP_BLOCKS + 1;   // 657

// ws layout (floats):
//   [0 .. KS*TOTQ)                 partial d^2 per (slice, query)   (10.5 MB)
//   [KS*TOTQ .. +K2_BLOCKS)        per-block chamfer distance sums (K2)
//   then TEMP_BLOCKS temporal partials, then 1 kl partial
constexpr size_t WS_PARTIAL = 0;
constexpr size_t WS_CHSUM   = (size_t)KS * TOTQ;
constexpr size_t WS_TPART   = WS_CHSUM + K2_BLOCKS;
constexpr size_t WS_KL      = WS_TPART + TEMP_BLOCKS;

// valid result on thread 0 only
__device__ __forceinline__ float block_sum(float v, float* red) {
    #pragma unroll
    for (int off = 32; off > 0; off >>= 1)
        v += __shfl_down(v, off, 64);
    const int wid = threadIdx.x >> 6;
    if ((threadIdx.x & 63) == 0) red[wid] = v;
    __syncthreads();
    return red[0] + red[1] + red[2] + red[3];
}

// ---------------------------------------------------------------------------
// K1: 1280 chamfer blocks (slice of 128 db points x all 2048 queries).
// Pure scalar-FMA formulation: same FMA-pipe cycles as packed, but no
// inline-asm pair-constraint movs (the ~1.8x VALU bloat seen in R0-R5).
// ---------------------------------------------------------------------------
__global__ __launch_bounds__(256) void k1_kernel(
        const float* __restrict__ pred, const float* __restrict__ tgt,
        float* __restrict__ ws) {
    __shared__ float4 db[SLICE];   // per point: {x, y, z, m = -0.5*|g|^2}

    const int bid = blockIdx.x;
    const int tid = threadIdx.x;

    const int ks  = bid & (KS - 1);
    const int dir = (bid >> 4) & 1;
    const int bs  = bid >> 5;                 // b*S + s  (0..39)
    const float* qb  = (dir ? tgt : pred) + (size_t)bs * N * 3;  // queries
    const float* dbp = (dir ? pred : tgt) + (size_t)bs * N * 3;  // database

    // stage 128 db points, one point per thread (tid < 128)
    if (tid < SLICE) {
        const int p0 = ks * SLICE + tid;
        const float x = dbp[3 * p0 + 0];
        const float y = dbp[3 * p0 + 1];
        const float z = dbp[3 * p0 + 2];
        db[tid] = make_float4(x, y, z, -0.5f * (x * x + y * y + z * z));
    }

    // load 8 queries into registers
    float px[QPT], py[QPT], pz[QPT], pn[QPT], acc[QPT];
    #pragma unroll
    for (int i = 0; i < QPT; ++i) {
        const int q = tid + THREADS * i;
        const float x = qb[3 * q + 0], y = qb[3 * q + 1], z = qb[3 * q + 2];
        px[i] = x;
        py[i] = y;
        pz[i] = z;
        pn[i] = x * x + y * y + z * z;
        acc[i] = -1e30f;
    }
    __syncthreads();

    // max over slice of score = p.g - 0.5|g|^2
    // per 2 db points per query: 6 v_fma_f32 + 1 v_max3_f32 = 14 SIMD-cycles
    #pragma unroll 2
    for (int p = 0; p < SLICE / 2; ++p) {
        const float4 g0 = db[2 * p + 0];
        const float4 g1 = db[2 * p + 1];
        #pragma unroll
        for (int i = 0; i < QPT; ++i) {
            float t0 = fmaf(pz[i], g0.z, g0.w);   // same z->y->x order as before
            t0 = fmaf(py[i], g0.y, t0);
            t0 = fmaf(px[i], g0.x, t0);
            float t1 = fmaf(pz[i], g1.z, g1.w);
            t1 = fmaf(py[i], g1.y, t1);
            t1 = fmaf(px[i], g1.x, t1);
            acc[i] = fmaxf(acc[i], fmaxf(t0, t1));   // fuses to v_max3_f32
        }
    }

    // partial d^2 for this slice (same values & global addresses as R5)
    float* part = ws + WS_PARTIAL + (size_t)ks * TOTQ + (size_t)(bs * 2 + dir) * N;
    #pragma unroll
    for (int i = 0; i < QPT; ++i)
        part[tid + THREADS * i] = pn[i] - 2.0f * acc[i];
}

// ---------------------------------------------------------------------------
// K2: blocks [0,640): per-query min over KS slices, sqrt, per-block sum;
//     blocks [640,656): temporal partials;  block 656: kl partial
//     (identical code & reduction order as the R5 k1 side-blocks)
// ---------------------------------------------------------------------------
__global__ __launch_bounds__(256) void k2_kernel(
        const float* __restrict__ pred,
        const float* __restrict__ prior_mean, const float* __restrict__ prior_lv,
        const float* __restrict__ post_mean,  const float* __restrict__ post_lv,
        float* __restrict__ ws) {
    __shared__ float red[4];
    const int bid = blockIdx.x;
    const int tid = threadIdx.x;

    if (bid < K2_BLOCKS) {
        const int u = bid * THREADS + tid;   // < TOTQ
        const float* part = ws + WS_PARTIAL;
        float d2 = part[u];
        #pragma unroll
        for (int k = 1; k < KS; ++k)
            d2 = fminf(d2, part[(size_t)k * TOTQ + u]);
        const float d = sqrtf(fmaxf(d2, 0.0f));
        const float tot = block_sum(d, red);
        if (tid == 0) ws[WS_CHSUM + bid] = tot;
    } else if (bid < K2_BLOCKS + TEMP_BLOCKS) {
        // temporal: sum ||pred[:,s+1]-pred[:,s]||
        const int tb = bid - K2_BLOCKS;
        float s = 0.0f;
        for (int it = 0; it < TEMP_PER_BLOCK / THREADS; ++it) {
            const int i = tb * TEMP_PER_BLOCK + it * THREADS + tid;
            const int b = i / ((S - 1) * N);
            const int r = i % ((S - 1) * N);
            const float* p0 = pred + (size_t)(b * S * N + r) * 3;
            const float* p1 = p0 + (size_t)N * 3;
            const float dx = p1[0] - p0[0];
            const float dy = p1[1] - p0[1];
            const float dz = p1[2] - p0[2];
            s += sqrtf(dx * dx + dy * dy + dz * dz);
        }
        const float tot = block_sum(s, red);
        if (tid == 0) ws[WS_TPART + tb] = tot;
    } else {
        // kl term sum
        float s = 0.0f;
        for (int it = 0; it < KL_ELEMS / THREADS; ++it) {
            const int i = it * THREADS + tid;
            const float a  = prior_lv[i];
            const float bb = post_lv[i];
            const float dm = post_mean[i] - prior_mean[i];
            s += a - bb + (expf(bb) + dm * dm) * expf(-a) - 1.0f;
        }
        const float tot = block_sum(s, red);
        if (tid == 0) ws[WS_KL] = tot;
    }
}

// ---------------------------------------------------------------------------
// K3: final combine (unchanged)
// ---------------------------------------------------------------------------
__global__ __launch_bounds__(256) void k3_kernel(const float* __restrict__ ws,
                                                 float* __restrict__ out) {
    __shared__ float red[4];
    float s = 0.0f;
    for (int i = threadIdx.x; i < K2_BLOCKS; i += THREADS)
        s += ws[WS_CHSUM + i];
    const float tot = block_sum(s, red);
    if (threadIdx.x == 0) {
        float tsum = 0.0f;
        for (int i = 0; i < TEMP_BLOCKS; ++i) tsum += ws[WS_TPART + i];
        const float recon    = tot / (float)(B * S * N);
        const float kl       = 0.5f * ws[WS_KL] / (float)(B * S);
        const float temporal = tsum / (float)TEMP_ELEMS;
        out[0] = recon + kl + 0.1f * temporal;
        out[1] = recon;
        out[2] = kl;
        out[3] = temporal;
        out[4] = 0.0f;
    }
}

extern "C" void kernel_launch(void* const* d_in, const int* in_sizes, int n_in,
                              void* d_out, int out_size, void* d_ws, size_t ws_size,
                              hipStream_t stream) {
    const float* pred = (const float*)d_in[0];
    const float* tgt  = (const float*)d_in[1];
    const float* pm   = (const float*)d_in[2];
    const float* plv  = (const float*)d_in[3];
    const float* qm   = (const float*)d_in[4];
    const float* qlv  = (const float*)d_in[5];
    float* out = (float*)d_out;
    float* ws  = (float*)d_ws;

    k1_kernel<<<CHAM_BLOCKS, THREADS, 0, stream>>>(pred, tgt, ws);
    k2_kernel<<<K2_GRID, THREADS, 0, stream>>>(pred, pm, plv, qm, qlv, ws);
    k3_kernel<<<1, THREADS, 0, stream>>>(ws, out);
}

// Round 7
// 97.688 us; speedup vs baseline: 1.5424x; 1.0613x over previous
//
#include <hip/hip_runtime.h>
#include <hip/hip_bf16.h>
#include <math.h>

// Problem constants (from reference setup_inputs)
constexpr int B = 4, S = 10, N = 2048, D = 128;

constexpr int THREADS = 256;
constexpr int GHALF   = 1024;           // db points per block (half of N)
constexpr int QBLK    = 256;            // queries per block
constexpr int QW      = 64;             // queries per wave (4 MFMA row-tiles)
constexpr int GT      = GHALF / 16;     // 64 g-tiles per block
constexpr int CHAM_BLOCKS = B * S * 2 * 2 * (N / QBLK);  // 40*2*2*8 = 1280
constexpr int TOTQ    = B * S * 2 * N;        // 163840 (query, dir) pairs
constexpr int TEMP_ELEMS = B * (S - 1) * N;   // 73728
constexpr int TEMP_BLOCKS = 16;
constexpr int TEMP_PER_BLOCK = TEMP_ELEMS / TEMP_BLOCKS;  // 4608
constexpr int KL_ELEMS = B * S * D;           // 5120
constexpr int K2_BLOCKS = TOTQ / THREADS;     // 640
constexpr int K2_GRID   = K2_BLOCKS + TEMP_BLOCKS + 1;   // 657

// ws layout (floats):
//   [0 .. 2*TOTQ)        per-(ghalf, query) max-score partials (1.3 MB)
//   [2*TOTQ .. +640)     per-block chamfer distance sums (K2)
//   then 16 temporal partials, then 1 kl partial
constexpr size_t WS_SMAX  = 0;
constexpr size_t WS_CHSUM = (size_t)2 * TOTQ;
constexpr size_t WS_TPART = WS_CHSUM + K2_BLOCKS;
constexpr size_t WS_KL    = WS_TPART + TEMP_BLOCKS;

typedef __attribute__((ext_vector_type(8))) short bf16x8;
typedef __attribute__((ext_vector_type(4))) float f32x4;

__device__ __forceinline__ unsigned short f2bf(float f) {   // RNE f32->bf16
    unsigned int b = __float_as_uint(f);
    b += 0x7FFFu + ((b >> 16) & 1u);
    return (unsigned short)(b >> 16);
}
__device__ __forceinline__ float bf2f(unsigned short h) {
    return __uint_as_float(((unsigned int)h) << 16);
}

// valid result on thread 0 only
__device__ __forceinline__ float block_sum(float v, float* red) {
    #pragma unroll
    for (int off = 32; off > 0; off >>= 1)
        v += __shfl_down(v, off, 64);
    const int wid = threadIdx.x >> 6;
    if ((threadIdx.x & 63) == 0) red[wid] = v;
    __syncthreads();
    return red[0] + red[1] + red[2] + red[3];
}

// ---------------------------------------------------------------------------
// K1: 1280 blocks: (bs, dir, ghalf, qgroup). MFMA score-matrix chamfer.
// One mfma_f32_16x16x32_bf16 per (16q x 16g) tile computes
//   ph*gh + pl*gh + ph*gl + (mh+ml+m3)  ~= p.g - 0.5|g|^2   (err ~1e-5)
// via K-slot packing:
//   k0-7  (lanes 0-15):  A=[phx,phy,phz,plx,ply,plz, 1, 0]
//                        B=[ghx,ghy,ghz,ghx,ghy,ghz, mh,ml]
//   k8-15 (lanes 16-31): A=[phx,phy,phz, 1, 0,0,0,0]
//                        B=[glx,gly,glz, m3,0,0,0,0]
//   k16-31 (lanes 32-63): zeros
// ---------------------------------------------------------------------------
__global__ __launch_bounds__(256) void k1_kernel(
        const float* __restrict__ pred, const float* __restrict__ tgt,
        float* __restrict__ ws) {
    __shared__ alignas(16) unsigned short ghm[GT][16][8];  // 16 KB
    __shared__ alignas(16) unsigned short glm[GT][16][8];  // 16 KB
    __shared__ alignas(16) unsigned short zbuf[8];

    const int bid = blockIdx.x;
    const int tid = threadIdx.x;
    const int qg  = bid & 7;
    const int gh  = (bid >> 3) & 1;
    const int dir = (bid >> 4) & 1;
    const int bs  = bid >> 5;                 // b*S + s  (0..39)
    const float* qb  = (dir ? tgt : pred) + (size_t)bs * N * 3;  // queries
    const float* dbp = (dir ? pred : tgt) + (size_t)bs * N * 3;  // database

    if (tid < 8) zbuf[tid] = 0;

    // stage 1024 db points as split-bf16 B-fragments
    #pragma unroll
    for (int k = 0; k < 4; ++k) {
        const int p  = tid + 256 * k;
        const int gp = gh * GHALF + p;
        const float x = dbp[3 * gp + 0];
        const float y = dbp[3 * gp + 1];
        const float z = dbp[3 * gp + 2];
        const unsigned short hx = f2bf(x), hy = f2bf(y), hz = f2bf(z);
        const unsigned short lx = f2bf(x - bf2f(hx));
        const unsigned short ly = f2bf(y - bf2f(hy));
        const unsigned short lz = f2bf(z - bf2f(hz));
        const float m  = -0.5f * (x * x + y * y + z * z);
        const unsigned short mh = f2bf(m);
        const float m1 = m - bf2f(mh);
        const unsigned short ml = f2bf(m1);
        const unsigned short m3 = f2bf(m1 - bf2f(ml));
        bf16x8 gv, lv;
        gv[0] = (short)hx; gv[1] = (short)hy; gv[2] = (short)hz;
        gv[3] = (short)hx; gv[4] = (short)hy; gv[5] = (short)hz;
        gv[6] = (short)mh; gv[7] = (short)ml;
        lv[0] = (short)lx; lv[1] = (short)ly; lv[2] = (short)lz;
        lv[3] = (short)m3; lv[4] = 0; lv[5] = 0; lv[6] = 0; lv[7] = 0;
        *(bf16x8*)&ghm[p >> 4][p & 15][0] = gv;
        *(bf16x8*)&glm[p >> 4][p & 15][0] = lv;
    }

    // A-fragments: 64 queries per wave, split-bf16, bias slot = 1.0
    const int lane = tid & 63, wid = tid >> 6;
    const int hi = lane >> 4, r = lane & 15;
    const int qwave = qg * QBLK + wid * QW;
    const short ONE = (short)0x3F80;
    bf16x8 a[4];
    #pragma unroll
    for (int qi = 0; qi < 4; ++qi) {
        bf16x8 v = (bf16x8)0;
        if (hi < 2) {
            const int q = qwave + qi * 16 + r;
            const float x = qb[3 * q + 0], y = qb[3 * q + 1], z = qb[3 * q + 2];
            const unsigned short hx = f2bf(x), hy = f2bf(y), hz = f2bf(z);
            if (hi == 0) {
                v[0] = (short)hx; v[1] = (short)hy; v[2] = (short)hz;
                v[3] = (short)f2bf(x - bf2f(hx));
                v[4] = (short)f2bf(y - bf2f(hy));
                v[5] = (short)f2bf(z - bf2f(hz));
                v[6] = ONE; v[7] = 0;
            } else {
                v[0] = (short)hx; v[1] = (short)hy; v[2] = (short)hz;
                v[3] = ONE;
            }
        }
        a[qi] = v;
    }
    __syncthreads();

    // per-lane B pointer: lanes 0-15 read ghm, 16-31 read glm, 32-63 zeros
    const char* bbase = (hi == 0) ? (const char*)&ghm[0][r][0]
                      : (hi == 1) ? (const char*)&glm[0][r][0]
                      :             (const char*)&zbuf[0];
    const int bstride = (hi < 2) ? 256 : 0;   // bytes per g-tile

    f32x4 rmax[4];
    #pragma unroll
    for (int qi = 0; qi < 4; ++qi) rmax[qi] = (f32x4)(-1e30f);
    const f32x4 zero4 = (f32x4)0.0f;

    for (int tp = 0; tp < GT / 2; ++tp) {
        const bf16x8 b0 = *(const bf16x8*)(bbase + (2 * tp + 0) * bstride);
        const bf16x8 b1 = *(const bf16x8*)(bbase + (2 * tp + 1) * bstride);
        #pragma unroll
        for (int qi = 0; qi < 4; ++qi) {
            const f32x4 c0 = __builtin_amdgcn_mfma_f32_16x16x32_bf16(a[qi], b0, zero4, 0, 0, 0);
            const f32x4 c1 = __builtin_amdgcn_mfma_f32_16x16x32_bf16(a[qi], b1, zero4, 0, 0, 0);
            #pragma unroll
            for (int j = 0; j < 4; ++j)
                rmax[qi][j] = fmaxf(rmax[qi][j], fmaxf(c0[j], c1[j]));  // v_max3
        }
    }

    // butterfly max across the 16 g-columns (C layout: col=lane&15,
    // row=(lane>>4)*4+j, verified m89)
    #pragma unroll
    for (int qi = 0; qi < 4; ++qi) {
        #pragma unroll
        for (int j = 0; j < 4; ++j) {
            float v = rmax[qi][j];
            v = fmaxf(v, __shfl_xor(v, 1, 64));
            v = fmaxf(v, __shfl_xor(v, 2, 64));
            v = fmaxf(v, __shfl_xor(v, 4, 64));
            v = fmaxf(v, __shfl_xor(v, 8, 64));
            rmax[qi][j] = v;
        }
    }
    if (r == 0) {
        float* base = ws + WS_SMAX + (size_t)gh * TOTQ
                    + (size_t)(bs * 2 + dir) * N + qwave;
        #pragma unroll
        for (int qi = 0; qi < 4; ++qi)
            #pragma unroll
            for (int j = 0; j < 4; ++j)
                base[qi * 16 + hi * 4 + j] = rmax[qi][j];
    }
}

// ---------------------------------------------------------------------------
// K2: blocks [0,640): per-query merge of 2 ghalf maxes, pn recompute (exact
//     fp32), sqrt, per-block sum; [640,656): temporal; 656: kl
// ---------------------------------------------------------------------------
__global__ __launch_bounds__(256) void k2_kernel(
        const float* __restrict__ pred, const float* __restrict__ tgt,
        const float* __restrict__ prior_mean, const float* __restrict__ prior_lv,
        const float* __restrict__ post_mean,  const float* __restrict__ post_lv,
        float* __restrict__ ws) {
    __shared__ float red[4];
    const int bid = blockIdx.x;
    const int tid = threadIdx.x;

    if (bid < K2_BLOCKS) {
        const int u = bid * THREADS + tid;   // < TOTQ
        const float s = fmaxf(ws[WS_SMAX + u], ws[WS_SMAX + TOTQ + u]);
        const int n   = u & (N - 1);
        const int bsd = u >> 11;             // (bs*2 + dir)
        const int dir = bsd & 1, bs = bsd >> 1;
        const float* q = (dir ? tgt : pred) + ((size_t)bs * N + n) * 3;
        const float x = q[0], y = q[1], z = q[2];
        const float pn = x * x + y * y + z * z;
        const float d = sqrtf(fmaxf(pn - 2.0f * s, 0.0f));
        const float tot = block_sum(d, red);
        if (tid == 0) ws[WS_CHSUM + bid] = tot;
    } else if (bid < K2_BLOCKS + TEMP_BLOCKS) {
        // temporal: sum ||pred[:,s+1]-pred[:,s]||
        const int tb = bid - K2_BLOCKS;
        float s = 0.0f;
        for (int it = 0; it < TEMP_PER_BLOCK / THREADS; ++it) {
            const int i = tb * TEMP_PER_BLOCK + it * THREADS + tid;
            const int b = i / ((S - 1) * N);
            const int rr = i % ((S - 1) * N);
            const float* p0 = pred + (size_t)(b * S * N + rr) * 3;
            const float* p1 = p0 + (size_t)N * 3;
            const float dx = p1[0] - p0[0];
            const float dy = p1[1] - p0[1];
            const float dz = p1[2] - p0[2];
            s += sqrtf(dx * dx + dy * dy + dz * dz);
        }
        const float tot = block_sum(s, red);
        if (tid == 0) ws[WS_TPART + tb] = tot;
    } else {
        // kl term sum
        float s = 0.0f;
        for (int it = 0; it < KL_ELEMS / THREADS; ++it) {
            const int i = it * THREADS + tid;
            const float aa = prior_lv[i];
            const float bb = post_lv[i];
            const float dm = post_mean[i] - prior_mean[i];
            s += aa - bb + (expf(bb) + dm * dm) * expf(-aa) - 1.0f;
        }
        const float tot = block_sum(s, red);
        if (tid == 0) ws[WS_KL] = tot;
    }
}

// ---------------------------------------------------------------------------
// K3: final combine (unchanged reduction order)
// ---------------------------------------------------------------------------
__global__ __launch_bounds__(256) void k3_kernel(const float* __restrict__ ws,
                                                 float* __restrict__ out) {
    __shared__ float red[4];
    float s = 0.0f;
    for (int i = threadIdx.x; i < K2_BLOCKS; i += THREADS)
        s += ws[WS_CHSUM + i];
    const float tot = block_sum(s, red);
    if (threadIdx.x == 0) {
        float tsum = 0.0f;
        for (int i = 0; i < TEMP_BLOCKS; ++i) tsum += ws[WS_TPART + i];
        const float recon    = tot / (float)(B * S * N);
        const float kl       = 0.5f * ws[WS_KL] / (float)(B * S);
        const float temporal = tsum / (float)TEMP_ELEMS;
        out[0] = recon + kl + 0.1f * temporal;
        out[1] = recon;
        out[2] = kl;
        out[3] = temporal;
        out[4] = 0.0f;
    }
}

extern "C" void kernel_launch(void* const* d_in, const int* in_sizes, int n_in,
                              void* d_out, int out_size, void* d_ws, size_t ws_size,
                              hipStream_t stream) {
    const float* pred = (const float*)d_in[0];
    const float* tgt  = (const float*)d_in[1];
    const float* pm   = (const float*)d_in[2];
    const float* plv  = (const float*)d_in[3];
    const float* qm   = (const float*)d_in[4];
    const float* qlv  = (const float*)d_in[5];
    float* out = (float*)d_out;
    float* ws  = (float*)d_ws;

    k1_kernel<<<CHAM_BLOCKS, THREADS, 0, stream>>>(pred, tgt, ws);
    k2_kernel<<<K2_GRID, THREADS, 0, stream>>>(pred, tgt, pm, plv, qm, qlv, ws);
    k3_kernel<<<1, THREADS, 0, stream>>>(ws, out);
}

// Round 8
// 82.621 us; speedup vs baseline: 1.8237x; 1.1824x over previous
//
#include <hip/hip_runtime.h>
#include <hip/hip_bf16.h>
#include <math.h>

// Problem constants (from reference setup_inputs)
constexpr int B = 4, S = 10, N = 2048, D = 128;

constexpr int THREADS = 512;          // 8 waves
constexpr int QBLK    = 256;          // queries per block (8 waves x 32 rows)
constexpr int NQG     = N / QBLK;     // 8 query groups
constexpr int GT      = N / 32;       // 64 g-tiles (32 db points each)
constexpr int CHAM_BLOCKS = B * S * 2 * NQG;   // 640
constexpr int TEMP_ELEMS = B * (S - 1) * N;    // 73728
constexpr int TEMP_BLOCKS = 16;
constexpr int TEMP_PER_BLOCK = TEMP_ELEMS / TEMP_BLOCKS;  // 4608 = 9*512
constexpr int KL_ELEMS = B * S * D;            // 5120 = 10*512
constexpr int K1_GRID  = CHAM_BLOCKS + TEMP_BLOCKS + 1;  // 657

// ws layout (floats): [0..640) chamfer block sums; [640..656) temporal; 656 kl
constexpr size_t WS_CHSUM = 0;
constexpr size_t WS_TPART = CHAM_BLOCKS;
constexpr size_t WS_KL    = WS_TPART + TEMP_BLOCKS;

typedef __attribute__((ext_vector_type(8)))  short bf16x8;
typedef __attribute__((ext_vector_type(16))) float f32x16;

__device__ __forceinline__ unsigned short f2bf(float f) {   // RNE f32->bf16
    unsigned int b = __float_as_uint(f);
    b += 0x7FFFu + ((b >> 16) & 1u);
    return (unsigned short)(b >> 16);
}
__device__ __forceinline__ float bf2f(unsigned short h) {
    return __uint_as_float(((unsigned int)h) << 16);
}

// valid on thread 0 only (512-thread blocks)
__device__ __forceinline__ float block_sum(float v, float* red) {
    #pragma unroll
    for (int off = 32; off > 0; off >>= 1)
        v += __shfl_down(v, off, 64);
    const int wid = threadIdx.x >> 6;
    if ((threadIdx.x & 63) == 0) red[wid] = v;
    __syncthreads();
    float s = 0.0f;
    if (threadIdx.x == 0)
        #pragma unroll
        for (int w = 0; w < 8; ++w) s += red[w];
    return s;
}

// ---------------------------------------------------------------------------
// K1 blocks [0,640): chamfer. block = (bs, dir, 256 queries) vs ALL 2048 g.
// One mfma_f32_32x32x16_bf16 per (32q x 32g) tile:
//   k0-7  (lanes 0-31):  A=[phx,phy,phz,plx,ply,plz, 1, 0]
//                        B=[ghx,ghy,ghz,ghx,ghy,ghz, mh,ml]
//   k8-15 (lanes 32-63): A=[phx,phy,phz, 1, 0,0,0,0]
//                        B=[glx,gly,glz, m3,0,0,0,0]
// score = ph.gh + pl.gh + ph.gl + (mh+ml+m3) ~= p.g - 0.5|g|^2  (err ~1e-5)
// Blocks [640,656): temporal.  Block 656: kl.
// ---------------------------------------------------------------------------
__global__ __launch_bounds__(512) void k1_kernel(
        const float* __restrict__ pred, const float* __restrict__ tgt,
        const float* __restrict__ prior_mean, const float* __restrict__ prior_lv,
        const float* __restrict__ post_mean,  const float* __restrict__ post_lv,
        float* __restrict__ ws) {
    __shared__ alignas(16) unsigned short bh[GT][32][8];  // 32 KB hi-pack
    __shared__ alignas(16) unsigned short bl[GT][32][8];  // 32 KB lo-pack
    __shared__ float sm[8][32];
    __shared__ float red[8];

    const int bid = blockIdx.x;
    const int tid = threadIdx.x;

    if (bid < CHAM_BLOCKS) {
        const int qg  = bid & (NQG - 1);
        const int dir = (bid >> 3) & 1;
        const int bs  = bid >> 4;                 // b*S + s  (0..39)
        const float* qb  = (dir ? tgt : pred) + (size_t)bs * N * 3;  // queries
        const float* dbp = (dir ? pred : tgt) + (size_t)bs * N * 3;  // database

        // ---- stage all 2048 db points as split-bf16 B-fragments ----
        // thread t does points {t, t+512, t+1024, t+1536}: dense 16B LDS stores
        #pragma unroll
        for (int j = 0; j < 4; ++j) {
            const int p = tid + 512 * j;
            const float x = dbp[3 * p + 0];
            const float y = dbp[3 * p + 1];
            const float z = dbp[3 * p + 2];
            const unsigned short hx = f2bf(x), hy = f2bf(y), hz = f2bf(z);
            const unsigned short lx = f2bf(x - bf2f(hx));
            const unsigned short ly = f2bf(y - bf2f(hy));
            const unsigned short lz = f2bf(z - bf2f(hz));
            const float m  = -0.5f * (x * x + y * y + z * z);
            const unsigned short mh = f2bf(m);
            const float m1 = m - bf2f(mh);
            const unsigned short ml = f2bf(m1);
            const unsigned short m3 = f2bf(m1 - bf2f(ml));
            bf16x8 gv, lv;
            gv[0] = (short)hx; gv[1] = (short)hy; gv[2] = (short)hz;
            gv[3] = (short)hx; gv[4] = (short)hy; gv[5] = (short)hz;
            gv[6] = (short)mh; gv[7] = (short)ml;
            lv[0] = (short)lx; lv[1] = (short)ly; lv[2] = (short)lz;
            lv[3] = (short)m3; lv[4] = 0; lv[5] = 0; lv[6] = 0; lv[7] = 0;
            *(bf16x8*)&bh[p >> 5][p & 31][0] = gv;
            *(bf16x8*)&bl[p >> 5][p & 31][0] = lv;
        }

        // ---- A-fragment: 32 query rows per wave, split-bf16, bias slot 1.0 ----
        const int lane = tid & 63, wid = tid >> 6;
        const int hi = lane >> 5, qr = lane & 31;
        const int q = qg * QBLK + wid * 32 + qr;
        const float qx = qb[3 * q + 0], qy = qb[3 * q + 1], qz = qb[3 * q + 2];
        const float pn = fmaf(qx, qx, fmaf(qy, qy, qz * qz));  // exact fp32 |p|^2
        const short ONE = (short)0x3F80;
        bf16x8 a;
        {
            const unsigned short hx = f2bf(qx), hy = f2bf(qy), hz = f2bf(qz);
            if (hi == 0) {
                a[0] = (short)hx; a[1] = (short)hy; a[2] = (short)hz;
                a[3] = (short)f2bf(qx - bf2f(hx));
                a[4] = (short)f2bf(qy - bf2f(hy));
                a[5] = (short)f2bf(qz - bf2f(hz));
                a[6] = ONE; a[7] = 0;
            } else {
                a[0] = (short)hx; a[1] = (short)hy; a[2] = (short)hz;
                a[3] = ONE; a[4] = 0; a[5] = 0; a[6] = 0; a[7] = 0;
            }
        }
        __syncthreads();

        // ---- main loop: 64 tiles, paired; 1 MFMA per 1024 scores ----
        const char* bbase = (hi ? (const char*)bl : (const char*)bh)
                          + (size_t)qr * 16;
        const f32x16 zero16 = (f32x16)0.0f;
        f32x16 rmax = (f32x16)(-1e30f);
        #pragma unroll 2
        for (int tp = 0; tp < GT / 2; ++tp) {
            const bf16x8 b0 = *(const bf16x8*)(bbase + (size_t)(2 * tp + 0) * 512);
            const bf16x8 b1 = *(const bf16x8*)(bbase + (size_t)(2 * tp + 1) * 512);
            const f32x16 c0 = __builtin_amdgcn_mfma_f32_32x32x16_bf16(a, b0, zero16, 0, 0, 0);
            const f32x16 c1 = __builtin_amdgcn_mfma_f32_32x32x16_bf16(a, b1, zero16, 0, 0, 0);
            #pragma unroll
            for (int j = 0; j < 16; ++j)
                rmax[j] = fmaxf(fmaxf(rmax[j], c0[j]), c1[j]);   // v_max3_f32
        }

        // ---- butterfly max over 32 g-columns (C: col=lane&31,
        //      row=(j&3)+8*(j>>2)+4*(lane>>5), verified m74/m101) ----
        #pragma unroll
        for (int j = 0; j < 16; ++j) {
            float v = rmax[j];
            v = fmaxf(v, __shfl_xor(v, 1, 64));
            v = fmaxf(v, __shfl_xor(v, 2, 64));
            v = fmaxf(v, __shfl_xor(v, 4, 64));
            v = fmaxf(v, __shfl_xor(v, 8, 64));
            v = fmaxf(v, __shfl_xor(v, 16, 64));
            rmax[j] = v;
        }
        if (qr == 0) {   // lanes 0 and 32: 16 rows each
            #pragma unroll
            for (int j = 0; j < 16; ++j)
                sm[wid][(j & 3) + 8 * (j >> 2) + 4 * hi] = rmax[j];
        }
        __syncthreads();

        // ---- d = sqrt(|p|^2 - 2*smax), per-block sum ----
        float d = 0.0f;
        if (lane < 32) {
            const float s = sm[wid][qr];
            d = sqrtf(fmaxf(pn - 2.0f * s, 0.0f));
        }
        const float tot = block_sum(d, red);
        if (tid == 0) ws[WS_CHSUM + bid] = tot;
    } else if (bid < CHAM_BLOCKS + TEMP_BLOCKS) {
        // temporal: sum ||pred[:,s+1]-pred[:,s]||
        const int tb = bid - CHAM_BLOCKS;
        float s = 0.0f;
        for (int it = 0; it < TEMP_PER_BLOCK / THREADS; ++it) {
            const int i = tb * TEMP_PER_BLOCK + it * THREADS + tid;
            const int b = i / ((S - 1) * N);
            const int rr = i % ((S - 1) * N);
            const float* p0 = pred + (size_t)(b * S * N + rr) * 3;
            const float* p1 = p0 + (size_t)N * 3;
            const float dx = p1[0] - p0[0];
            const float dy = p1[1] - p0[1];
            const float dz = p1[2] - p0[2];
            s += sqrtf(dx * dx + dy * dy + dz * dz);
        }
        const float tot = block_sum(s, red);
        if (tid == 0) ws[WS_TPART + tb] = tot;
    } else {
        // kl term sum
        float s = 0.0f;
        for (int it = 0; it < KL_ELEMS / THREADS; ++it) {
            const int i = it * THREADS + tid;
            const float aa = prior_lv[i];
            const float bb = post_lv[i];
            const float dm = post_mean[i] - prior_mean[i];
            s += aa - bb + (expf(bb) + dm * dm) * expf(-aa) - 1.0f;
        }
        const float tot = block_sum(s, red);
        if (tid == 0) ws[WS_KL] = tot;
    }
}

// ---------------------------------------------------------------------------
// K3: final combine
// ---------------------------------------------------------------------------
__global__ __launch_bounds__(512) void k3_kernel(const float* __restrict__ ws,
                                                 float* __restrict__ out) {
    __shared__ float red[8];
    float s = 0.0f;
    for (int i = threadIdx.x; i < CHAM_BLOCKS; i += THREADS)
        s += ws[WS_CHSUM + i];
    const float tot = block_sum(s, red);
    if (threadIdx.x == 0) {
        float tsum = 0.0f;
        for (int i = 0; i < TEMP_BLOCKS; ++i) tsum += ws[WS_TPART + i];
        const float recon    = tot / (float)(B * S * N);
        const float kl       = 0.5f * ws[WS_KL] / (float)(B * S);
        const float temporal = tsum / (float)TEMP_ELEMS;
        out[0] = recon + kl + 0.1f * temporal;
        out[1] = recon;
        out[2] = kl;
        out[3] = temporal;
        out[4] = 0.0f;
    }
}

extern "C" void kernel_launch(void* const* d_in, const int* in_sizes, int n_in,
                              void* d_out, int out_size, void* d_ws, size_t ws_size,
                              hipStream_t stream) {
    const float* pred = (const float*)d_in[0];
    const float* tgt  = (const float*)d_in[1];
    const float* pm   = (const float*)d_in[2];
    const float* plv  = (const float*)d_in[3];
    const float* qm   = (const float*)d_in[4];
    const float* qlv  = (const float*)d_in[5];
    float* out = (float*)d_out;
    float* ws  = (float*)d_ws;

    k1_kernel<<<K1_GRID, THREADS, 0, stream>>>(pred, tgt, pm, plv, qm, qlv, ws);
    k3_kernel<<<1, THREADS, 0, stream>>>(ws, out);
}